// Round 2
// baseline (684.271 us; speedup 1.0000x reference)
//
#include <hip/hip_runtime.h>
#include <hip/hip_bf16.h>

// sigmoid(x) = 1 / (1 + e^-x); __expf -> v_mul + v_exp_f32, rcpf -> v_rcp_f32.
// Avoids the IEEE divide expansion without -ffast-math.
__device__ __forceinline__ float sigmoidf_fast(float v) {
    return __builtin_amdgcn_rcpf(1.0f + __expf(-v));
}

__global__ __launch_bounds__(256) void mesh_weights_kernel(
    const float* __restrict__ points,
    const int*   __restrict__ adj,
    const float* __restrict__ W1, const float* __restrict__ b1,
    const float* __restrict__ W2, const float* __restrict__ b2,
    const float* __restrict__ W3, const float* __restrict__ b3,
    const float* __restrict__ W4, const float* __restrict__ b4,
    float* __restrict__ out,
    int n_elems)
{
    const int e = blockIdx.x * 256 + threadIdx.x;
    if (e >= n_elems) return;

    // ---- gather: 3 vertex indices, 3 float2 coords ----
    const int i0 = adj[3 * e + 0];
    const int i1 = adj[3 * e + 1];
    const int i2 = adj[3 * e + 2];
    const float2* pts2 = (const float2*)points;
    const float2 p0 = pts2[i0];
    const float2 p1 = pts2[i1];
    const float2 p2 = pts2[i2];

    const float x[6] = { p0.x, p0.y, p1.x, p1.y, p2.x, p2.y };

    // All weight/bias loads below use wave-uniform addresses (const __restrict__
    // kernel args + compile-time indices) -> compiler emits scalar s_load into
    // SGPRs; v_fma_f32 takes the SGPR operand directly. No LDS staging.

    // ---- layer 1: 6 -> 8 ----
    float h[8], g[8];
    #pragma unroll
    for (int j = 0; j < 8; ++j) h[j] = b1[j];
    #pragma unroll
    for (int i = 0; i < 6; ++i) {
        const float xi = x[i];
        #pragma unroll
        for (int j = 0; j < 8; ++j) h[j] = fmaf(xi, W1[i * 8 + j], h[j]);
    }
    #pragma unroll
    for (int j = 0; j < 8; ++j) h[j] = sigmoidf_fast(h[j]);

    // ---- layer 2: 8 -> 8 ----
    #pragma unroll
    for (int j = 0; j < 8; ++j) g[j] = b2[j];
    #pragma unroll
    for (int i = 0; i < 8; ++i) {
        const float hi = h[i];
        #pragma unroll
        for (int j = 0; j < 8; ++j) g[j] = fmaf(hi, W2[i * 8 + j], g[j]);
    }
    #pragma unroll
    for (int j = 0; j < 8; ++j) g[j] = sigmoidf_fast(g[j]);

    // ---- layer 3: 8 -> 8 ----
    #pragma unroll
    for (int j = 0; j < 8; ++j) h[j] = b3[j];
    #pragma unroll
    for (int i = 0; i < 8; ++i) {
        const float gi = g[i];
        #pragma unroll
        for (int j = 0; j < 8; ++j) h[j] = fmaf(gi, W3[i * 8 + j], h[j]);
    }
    #pragma unroll
    for (int j = 0; j < 8; ++j) h[j] = sigmoidf_fast(h[j]);

    // ---- layer 4: 8 -> 3 ----
    float o0 = b4[0], o1 = b4[1], o2 = b4[2];
    #pragma unroll
    for (int i = 0; i < 8; ++i) {
        const float hi = h[i];
        o0 = fmaf(hi, W4[i * 3 + 0], o0);
        o1 = fmaf(hi, W4[i * 3 + 1], o1);
        o2 = fmaf(hi, W4[i * 3 + 2], o2);
    }
    o0 = sigmoidf_fast(o0);
    o1 = sigmoidf_fast(o1);
    o2 = sigmoidf_fast(o2);

    // ---- scatter-add back to vertices (device-scope fp32 atomics) ----
    atomicAdd(&out[i0], o0);
    atomicAdd(&out[i1], o1);
    atomicAdd(&out[i2], o2);
}

extern "C" void kernel_launch(void* const* d_in, const int* in_sizes, int n_in,
                              void* d_out, int out_size, void* d_ws, size_t ws_size,
                              hipStream_t stream) {
    const float* points = (const float*)d_in[0];
    const int*   adj    = (const int*)d_in[1];
    const float* W1 = (const float*)d_in[2];
    const float* b1 = (const float*)d_in[3];
    const float* W2 = (const float*)d_in[4];
    const float* b2 = (const float*)d_in[5];
    const float* W3 = (const float*)d_in[6];
    const float* b3 = (const float*)d_in[7];
    const float* W4 = (const float*)d_in[8];
    const float* b4 = (const float*)d_in[9];
    float* out = (float*)d_out;

    const int n_elems = in_sizes[1] / 3;  // adjacency is [E,3]

    // d_out is re-poisoned (0xAA) before every timed launch -> zero it here.
    hipMemsetAsync(out, 0, (size_t)out_size * sizeof(float), stream);

    const int block = 256;
    const int grid = (n_elems + block - 1) / block;
    mesh_weights_kernel<<<grid, block, 0, stream>>>(
        points, adj, W1, b1, W2, b2, W3, b3, W4, b4, out, n_elems);
}

// Round 3
// 682.323 us; speedup vs baseline: 1.0029x; 1.0029x over previous
//
#include <hip/hip_runtime.h>
#include <hip/hip_bf16.h>

// sigmoid(x) = 1 / (1 + e^-x); __expf -> v_mul + v_exp_f32, rcpf -> v_rcp_f32.
__device__ __forceinline__ float sigmoidf_fast(float v) {
    return __builtin_amdgcn_rcpf(1.0f + __expf(-v));
}

__global__ __launch_bounds__(256) void mesh_weights_kernel(
    const float* __restrict__ points,
    const int*   __restrict__ adj,
    const float* __restrict__ W1, const float* __restrict__ b1,
    const float* __restrict__ W2, const float* __restrict__ b2,
    const float* __restrict__ W3, const float* __restrict__ b3,
    const float* __restrict__ W4, const float* __restrict__ b4,
    float* __restrict__ out,
    int n_elems)
{
    const int e = blockIdx.x * 256 + threadIdx.x;
    if (e >= n_elems) return;

    // ---- gather: 3 vertex indices, 3 float2 coords ----
    const int i0 = adj[3 * e + 0];
    const int i1 = adj[3 * e + 1];
    const int i2 = adj[3 * e + 2];
    const float2* pts2 = (const float2*)points;
    const float2 p0 = pts2[i0];
    const float2 p1 = pts2[i1];
    const float2 p2 = pts2[i2];

    const float x[6] = { p0.x, p0.y, p1.x, p1.y, p2.x, p2.y };

    // Weight loads are wave-uniform -> scalar s_load into SGPRs (free).

    // ---- layer 1: 6 -> 8 ----
    float h[8], g[8];
    #pragma unroll
    for (int j = 0; j < 8; ++j) h[j] = b1[j];
    #pragma unroll
    for (int i = 0; i < 6; ++i) {
        const float xi = x[i];
        #pragma unroll
        for (int j = 0; j < 8; ++j) h[j] = fmaf(xi, W1[i * 8 + j], h[j]);
    }
    #pragma unroll
    for (int j = 0; j < 8; ++j) h[j] = sigmoidf_fast(h[j]);

    // ---- layer 2: 8 -> 8 ----
    #pragma unroll
    for (int j = 0; j < 8; ++j) g[j] = b2[j];
    #pragma unroll
    for (int i = 0; i < 8; ++i) {
        const float hi = h[i];
        #pragma unroll
        for (int j = 0; j < 8; ++j) g[j] = fmaf(hi, W2[i * 8 + j], g[j]);
    }
    #pragma unroll
    for (int j = 0; j < 8; ++j) g[j] = sigmoidf_fast(g[j]);

    // ---- layer 3: 8 -> 8 ----
    #pragma unroll
    for (int j = 0; j < 8; ++j) h[j] = b3[j];
    #pragma unroll
    for (int i = 0; i < 8; ++i) {
        const float gi = g[i];
        #pragma unroll
        for (int j = 0; j < 8; ++j) h[j] = fmaf(gi, W3[i * 8 + j], h[j]);
    }
    #pragma unroll
    for (int j = 0; j < 8; ++j) h[j] = sigmoidf_fast(h[j]);

    // ---- layer 4: 8 -> 3 ----
    float o0 = b4[0], o1 = b4[1], o2 = b4[2];
    #pragma unroll
    for (int i = 0; i < 8; ++i) {
        const float hi = h[i];
        o0 = fmaf(hi, W4[i * 3 + 0], o0);
        o1 = fmaf(hi, W4[i * 3 + 1], o1);
        o2 = fmaf(hi, W4[i * 3 + 2], o2);
    }
    o0 = sigmoidf_fast(o0);
    o1 = sigmoidf_fast(o1);
    o2 = sigmoidf_fast(o2);

    // ---- scatter-add: native HW fp32 atomics (global_atomic_add_f32),
    // fire-and-forget, no CAS loop. Memory is coarse-grained (hipMalloc),
    // so the unsafe (non-CAS) path is correct at device scope.
    unsafeAtomicAdd(&out[i0], o0);
    unsafeAtomicAdd(&out[i1], o1);
    unsafeAtomicAdd(&out[i2], o2);
}

extern "C" void kernel_launch(void* const* d_in, const int* in_sizes, int n_in,
                              void* d_out, int out_size, void* d_ws, size_t ws_size,
                              hipStream_t stream) {
    const float* points = (const float*)d_in[0];
    const int*   adj    = (const int*)d_in[1];
    const float* W1 = (const float*)d_in[2];
    const float* b1 = (const float*)d_in[3];
    const float* W2 = (const float*)d_in[4];
    const float* b2 = (const float*)d_in[5];
    const float* W3 = (const float*)d_in[6];
    const float* b3 = (const float*)d_in[7];
    const float* W4 = (const float*)d_in[8];
    const float* b4 = (const float*)d_in[9];
    float* out = (float*)d_out;

    const int n_elems = in_sizes[1] / 3;  // adjacency is [E,3]

    // d_out is re-poisoned (0xAA) before every timed launch -> zero it here.
    hipMemsetAsync(out, 0, (size_t)out_size * sizeof(float), stream);

    const int block = 256;
    const int grid = (n_elems + block - 1) / block;
    mesh_weights_kernel<<<grid, block, 0, stream>>>(
        points, adj, W1, b1, W2, b2, W3, b3, W4, b4, out, n_elems);
}